// Round 9
// baseline (103.329 us; speedup 1.0000x reference)
//
#include <hip/hip_runtime.h>
#include <stdint.h>

#define NPTS 16384

typedef __attribute__((ext_vector_type(8)))  __bf16   bf16x8;
typedef __attribute__((ext_vector_type(16))) float    f32x16;
typedef __attribute__((ext_vector_type(4)))  uint32_t u32x4;

struct PrepArgs { const float* W[7]; u32x4* dst; };

struct Args {
    const float* W0; const float* b0;
    const float* bias[8];   // [1..7] valid
    const float* W8; const float* b8;
    const float* xs; const float* ys; const float* ts;
    const float* l1; const float* l2;
    const u32x4* wpk;       // packed W frags in d_ws
    float* out;
};

// ---------- bf16 helpers (verified) ----------
__device__ __forceinline__ uint32_t b16rne(float x) {
    uint32_t u = __float_as_uint(x);
    return (u + 0x7FFFu + ((u >> 16) & 1u)) >> 16;
}
__device__ __forceinline__ float fromb16(uint32_t h) { return __uint_as_float(h << 16); }

__device__ __forceinline__ void packPair(float a, float b, uint32_t& hw, uint32_t& lw) {
    uint32_t ha = b16rne(a), hb = b16rne(b);
    float la = a - fromb16(ha), lb = b - fromb16(hb);
    hw = ha | (hb << 16);
    lw = b16rne(la) | (b16rne(lb) << 16);
}

// packed RNE bf16 pair: low16 = bf16(a), high16 = bf16(b)
__device__ __forceinline__ uint32_t cvtpk_bf16(float a, float b) {
    uint32_t r;
    asm("v_cvt_pk_bf16_f32 %0, %1, %2" : "=v"(r) : "v"(a), "v"(b));
    return r;
}

__device__ __forceinline__ f32x16 mfma16(bf16x8 a, bf16x8 b, f32x16 c) {
    return __builtin_amdgcn_mfma_f32_32x32x16_bf16(a, b, c, 0, 0, 0);
}

__device__ __forceinline__ float fast_tanh(float x) {
    float e = __expf(2.0f * x);
    return 1.0f - __fdividef(2.0f, e + 1.0f);   // inf-safe
}

// ---------- full 13-channel tanh jet (verified, fallback path) ----------
__device__ __forceinline__ void tanh_jet(float u[13]) {
    float s    = fast_tanh(u[0]);
    float sp   = 1.f - s * s;
    float spp  = -2.f * s * sp;
    float sppp = -2.f * (sp * sp + s * spp);
    float u1 = u[1], u2 = u[2], u3 = u[3];
    float u4 = u[4], u5 = u[5], u6 = u[6];
    u[0] = s;
    u[1] = sp * u1;
    u[2] = sp * u2;
    u[3] = sp * u3;
    u[9]  = sppp * u1 * u1 * u1 + 3.f * spp * u1 * u4 + sp * u[9];
    u[10] = sppp * u1 * u1 * u2 + spp * (u4 * u2 + 2.f * u5 * u1) + sp * u[10];
    u[11] = sppp * u1 * u2 * u2 + spp * (u6 * u1 + 2.f * u5 * u2) + sp * u[11];
    u[12] = sppp * u2 * u2 * u2 + 3.f * spp * u2 * u6 + sp * u[12];
    u[4] = spp * u1 * u1 + sp * u4;
    u[5] = spp * u1 * u2 + sp * u5;
    u[6] = spp * u2 * u2 + sp * u6;
    u[7] = spp * u1 * u3 + sp * u[7];
    u[8] = spp * u2 * u3 + sp * u[8];
}

// ---------- reduced 6-channel jet: 0:val 1:dx 2:dy 3:dt 4:dxt 5:dyt ----------
__device__ __forceinline__ void tanh_jet6(float u[6]) {
    float s   = fast_tanh(u[0]);
    float sp  = 1.f - s * s;
    float spp = -2.f * s * sp;
    float u1 = u[1], u2 = u[2], u3 = u[3];
    u[0] = s;
    u[4] = spp * u1 * u3 + sp * u[4];
    u[5] = spp * u2 * u3 + sp * u[5];
    u[1] = sp * u1;
    u[2] = sp * u2;
    u[3] = sp * u3;
}

// ---------- prep: pack W1..W7 into B-frag order (verified, unchanged) ----------
__global__ __launch_bounds__(256)
void pack_w_kernel(PrepArgs a) {
    int idx = blockIdx.x * 256 + threadIdx.x;   // 7*16*128 = 14336
    int L  = idx >> 11;
    int kb = (idx >> 7) & 15;
    int n  = idx & 127;
    const float* w = a.W[L] + n * 128 + kb * 8;
    float4 f0 = *(const float4*)w;
    float4 f1 = *(const float4*)(w + 4);
    uint32_t h0, h1, h2, h3, l0, l1, l2, l3;
    packPair(f0.x, f0.y, h0, l0);
    packPair(f0.z, f0.w, h1, l1);
    packPair(f1.x, f1.y, h2, l2);
    packPair(f1.z, f1.w, h3, l3);
    a.dst[((L * 2 + 0) * 16 + kb) * 128 + n] = u32x4{h0, h1, h2, h3};
    a.dst[((L * 2 + 1) * 16 + kb) * 128 + n] = u32x4{l0, l1, l2, l3};
}

// ================= reduced path: lambda1 == lambda2 == 0 =================
// 16 points/block, M=96 rows = 3 MFMA tiles, ZERO pad rows.
// Slot u = 6q + c  (q = local point 0..7 within kh-class, c = channel 0..5);
//   t = u>>4 (tile), i = u&15 (acc register index),
//   row = 32t + (i&3) + 8*(i>>2) + 4*kh;  point p = q + 8*kh.
// Channel pairs (c even) are always row-adjacent within one tile.
// A: two bf16 planes [96][128], 16B-granule XOR swizzle (verified):
//   addr(row,k) = row*128 + (((k>>3) ^ (row&15))<<3) + (k&7)
__global__ __launch_bounds__(256, 3)
void pinn_red16_kernel(Args args)
{
    if (args.l1[0] != 0.f || args.l2[0] != 0.f) return;   // uniform guard

    __shared__ ushort Ahi[96 * 128];        // 24 KB
    __shared__ ushort Alo[96 * 128];        // 24 KB
    __shared__ float  Part[4][2][8][9];     // 2.25 KB [wid][kh][q][v]

    const int tid   = threadIdx.x;
    const int lane  = tid & 63;
    const int wid   = tid >> 6;
    const int ln31  = lane & 31;
    const int kh    = lane >> 5;
    const int n     = wid * 32 + ln31;      // this lane's neuron
    const int pbase = blockIdx.x * 16;

    auto put_pair = [&](float dA, float dB, int rowA) {
        const int rowB = rowA + 1;
        const int aA = rowA * 128 + ((((n >> 3) ^ (rowA & 15)) << 3) | (n & 7));
        const int aB = rowB * 128 + ((((n >> 3) ^ (rowB & 15)) << 3) | (n & 7));
        uint32_t hp = cvtpk_bf16(dA, dB);
        float hA = __uint_as_float(hp << 16);
        float hB = __uint_as_float(hp & 0xFFFF0000u);
        uint32_t lp = cvtpk_bf16(dA - hA, dB - hB);
        Ahi[aA] = (ushort)hp;  Ahi[aB] = (ushort)(hp >> 16);
        Alo[aA] = (ushort)lp;  Alo[aB] = (ushort)(lp >> 16);
    };
    // store jet for local point q: pairs at slots u = 6q+{0,2,4}
    auto store_jet6 = [&](const float d[6], int q) {
        #pragma unroll
        for (int cp = 0; cp < 3; ++cp) {
            const int u = 6 * q + 2 * cp;
            const int t = u >> 4, i = u & 15;
            const int rowA = 32 * t + (i & 3) + 8 * (i >> 2) + 4 * kh;
            put_pair(d[2 * cp], d[2 * cp + 1], rowA);
        }
    };

    // ---- layer 0: closed-form 6-jets; lane handles 8 points (its kh-class) ----
    {
        float w0 = args.W0[n * 3], w1 = args.W0[n * 3 + 1], w2 = args.W0[n * 3 + 2];
        float bb = args.b0[n];
        #pragma unroll
        for (int q = 0; q < 8; ++q) {
            const int p = q + 8 * kh;
            float x = args.xs[pbase + p], y = args.ys[pbase + p], tt = args.ts[pbase + p];
            float d[6];
            d[0] = w0 * x + w1 * y + w2 * tt + bb;
            d[1] = w0; d[2] = w1; d[3] = w2;
            d[4] = 0.f; d[5] = 0.f;
            tanh_jet6(d);
            store_jet6(d, q);
        }
    }
    __syncthreads();

    for (int L = 1; L <= 7; ++L) {
        const u32x4* whi = args.wpk + (size_t)(L - 1) * 4096;
        const u32x4* wlo = whi + 2048;
        f32x16 acc0{}, acc1{}, acc2{};

        #pragma unroll
        for (int ks = 0; ks < 8; ++ks) {
            const int kb = ks * 2 + kh;
            const u32x4 rbh = whi[kb * 128 + n];
            const u32x4 rbl = wlo[kb * 128 + n];

            const int koff = (kb ^ (ln31 & 15)) << 3;
            const int e0 = (ln31     ) * 128 + koff;
            const int e1 = (ln31 + 32) * 128 + koff;
            const int e2 = (ln31 + 64) * 128 + koff;
            bf16x8 ah0 = __builtin_bit_cast(bf16x8, *(const u32x4*)&Ahi[e0]);
            bf16x8 ah1 = __builtin_bit_cast(bf16x8, *(const u32x4*)&Ahi[e1]);
            bf16x8 ah2 = __builtin_bit_cast(bf16x8, *(const u32x4*)&Ahi[e2]);
            bf16x8 al0 = __builtin_bit_cast(bf16x8, *(const u32x4*)&Alo[e0]);
            bf16x8 al1 = __builtin_bit_cast(bf16x8, *(const u32x4*)&Alo[e1]);
            bf16x8 al2 = __builtin_bit_cast(bf16x8, *(const u32x4*)&Alo[e2]);
            bf16x8 bh  = __builtin_bit_cast(bf16x8, rbh);
            bf16x8 bl  = __builtin_bit_cast(bf16x8, rbl);

            acc0 = mfma16(ah0, bh, acc0);
            acc1 = mfma16(ah1, bh, acc1);
            acc2 = mfma16(ah2, bh, acc2);
            acc0 = mfma16(al0, bh, acc0);
            acc1 = mfma16(al1, bh, acc1);
            acc2 = mfma16(al2, bh, acc2);
            acc0 = mfma16(ah0, bl, acc0);
            acc1 = mfma16(ah1, bl, acc1);
            acc2 = mfma16(ah2, bl, acc2);
        }

        __syncthreads();   // all waves finished reading A

        const float bL = args.bias[L][n];

        if (L < 7) {
            #pragma unroll
            for (int q = 0; q < 8; ++q) {
                float d[6];
                #pragma unroll
                for (int c = 0; c < 6; ++c) {
                    const int u = 6 * q + c, t = u >> 4, i = u & 15;
                    d[c] = (t == 0) ? acc0[i] : (t == 1) ? acc1[i] : acc2[i];
                }
                d[0] += bL;
                tanh_jet6(d);
                store_jet6(d, q);
            }
            __syncthreads();   // A ready for next layer
        } else {
            const float wp = args.W8[n], wq = args.W8[128 + n];
            #pragma unroll
            for (int q = 0; q < 8; ++q) {
                float d[6];
                #pragma unroll
                for (int c = 0; c < 6; ++c) {
                    const int u = 6 * q + c, t = u >> 4, i = u & 15;
                    d[c] = (t == 0) ? acc0[i] : (t == 1) ? acc1[i] : acc2[i];
                }
                d[0] += bL;
                tanh_jet6(d);
                float rp[9];
                #pragma unroll
                for (int c = 0; c < 6; ++c) rp[c] = wp * d[c];
                rp[6] = wq * d[0]; rp[7] = wq * d[1]; rp[8] = wq * d[2];
                #pragma unroll
                for (int v = 0; v < 9; ++v) {
                    float s = rp[v];
                    s += __shfl_xor(s, 16); s += __shfl_xor(s, 8);
                    s += __shfl_xor(s, 4);  s += __shfl_xor(s, 2);
                    s += __shfl_xor(s, 1);
                    rp[v] = s;
                }
                if (ln31 == 0) {
                    #pragma unroll
                    for (int v = 0; v < 9; ++v) Part[wid][kh][q][v] = rp[v];
                }
            }
        }
    }

    __syncthreads();   // Part visible

    if (tid < 16) {
        const int p = tid, khp = p >> 3, q = p & 7;
        float s[9];
        #pragma unroll
        for (int v = 0; v < 9; ++v)
            s[v] = Part[0][khp][q][v] + Part[1][khp][q][v]
                 + Part[2][khp][q][v] + Part[3][khp][q][v];

        float u   = s[2];              // psi_y
        float v   = -s[1];             // -psi_x
        float pv  = s[6] + args.b8[1]; // p
        float f_u = s[5] + s[7];       // psi_yt + p_x      (lambda = 0)
        float f_v = -s[4] + s[8];      // -psi_xt + p_y
        const int pt = pbase + p;
        float* out = args.out;
        out[0 * NPTS + pt] = u;
        out[1 * NPTS + pt] = v;
        out[2 * NPTS + pt] = pv;
        out[3 * NPTS + pt] = f_u;
        out[4 * NPTS + pt] = f_v;
    }
}

// ================= full path (R7-verified), runs only when lambda != 0 =========
__global__ __launch_bounds__(256, 2)
void pinn_mfma6_kernel(Args args)
{
    if (args.l1[0] == 0.f && args.l2[0] == 0.f) return;   // reduced path handles it

    __shared__ ushort Ahi[128 * 128];       // 32 KB
    __shared__ ushort Alo[128 * 128];       // 32 KB
    __shared__ float  Part[4][2][4][16];    // 2 KB

    const int tid   = threadIdx.x;
    const int lane  = tid & 63;
    const int wid   = tid >> 6;
    const int ln31  = lane & 31;
    const int kh    = lane >> 5;
    const int n     = wid * 32 + ln31;
    const int pbase = blockIdx.x * 8;

    auto store_jet = [&](const float d[13], int j) {
        const int rb = 32 * j + 4 * kh;
        #pragma unroll
        for (int cp = 0; cp < 6; ++cp) {
            const int cA = 2 * cp, cB = cA + 1;
            const int rowA = rb + 8 * (cA >> 2) + (cA & 3);
            const int rowB = rb + 8 * (cB >> 2) + (cB & 3);
            const int aA = rowA * 128 + ((((n >> 3) ^ (rowA & 15)) << 3) | (n & 7));
            const int aB = rowB * 128 + ((((n >> 3) ^ (rowB & 15)) << 3) | (n & 7));
            uint32_t hp = cvtpk_bf16(d[cA], d[cB]);
            float hA = __uint_as_float(hp << 16);
            float hB = __uint_as_float(hp & 0xFFFF0000u);
            uint32_t lp = cvtpk_bf16(d[cA] - hA, d[cB] - hB);
            Ahi[aA] = (ushort)hp; Ahi[aB] = (ushort)(hp >> 16);
            Alo[aA] = (ushort)lp; Alo[aB] = (ushort)(lp >> 16);
        }
        {
            const int row = rb + 24;
            const int a12 = row * 128 + ((((n >> 3) ^ (row & 15)) << 3) | (n & 7));
            uint32_t hp = cvtpk_bf16(d[12], 0.f);
            float h = __uint_as_float(hp << 16);
            uint32_t lp = cvtpk_bf16(d[12] - h, 0.f);
            Ahi[a12] = (ushort)hp;
            Alo[a12] = (ushort)lp;
        }
    };

    {
        float w0 = args.W0[n * 3], w1 = args.W0[n * 3 + 1], w2 = args.W0[n * 3 + 2];
        float bb = args.b0[n];
        #pragma unroll
        for (int j = 0; j < 4; ++j) {
            const int p = j + 4 * kh;
            float x = args.xs[pbase + p], y = args.ys[pbase + p], t = args.ts[pbase + p];
            float d[13];
            #pragma unroll
            for (int c = 4; c < 13; ++c) d[c] = 0.f;
            d[0] = w0 * x + w1 * y + w2 * t + bb;
            d[1] = w0; d[2] = w1; d[3] = w2;
            tanh_jet(d);
            store_jet(d, j);
        }
        #pragma unroll
        for (int i = 0; i < 12; ++i) {
            int idx  = tid + 256 * i;
            int pl   = (idx >= 1536) ? 1 : 0;
            int rem  = idx - 1536 * pl;
            int rowi = rem >> 6;
            int w    = rem & 63;
            int t4   = rowi / 6, s = rowi - 6 * t4;
            int row  = 32 * t4 + 24 + 4 * (s / 3) + 1 + (s % 3);
            uint32_t* P = pl ? (uint32_t*)Alo : (uint32_t*)Ahi;
            P[row * 64 + w] = 0;
        }
    }
    __syncthreads();

    for (int L = 1; L <= 7; ++L) {
        const u32x4* whi = args.wpk + (size_t)(L - 1) * 4096;
        const u32x4* wlo = whi + 2048;
        f32x16 acc0{}, acc1{}, acc2{}, acc3{};

        #pragma unroll
        for (int ks = 0; ks < 8; ++ks) {
            const int kb = ks * 2 + kh;
            const u32x4 rbh = whi[kb * 128 + n];
            const u32x4 rbl = wlo[kb * 128 + n];

            const int koff = (kb ^ (ln31 & 15)) << 3;
            const int e0 = (ln31      ) * 128 + koff;
            const int e1 = (ln31 + 32 ) * 128 + koff;
            const int e2 = (ln31 + 64 ) * 128 + koff;
            const int e3 = (ln31 + 96 ) * 128 + koff;
            bf16x8 ah0 = __builtin_bit_cast(bf16x8, *(const u32x4*)&Ahi[e0]);
            bf16x8 ah1 = __builtin_bit_cast(bf16x8, *(const u32x4*)&Ahi[e1]);
            bf16x8 ah2 = __builtin_bit_cast(bf16x8, *(const u32x4*)&Ahi[e2]);
            bf16x8 ah3 = __builtin_bit_cast(bf16x8, *(const u32x4*)&Ahi[e3]);
            bf16x8 al0 = __builtin_bit_cast(bf16x8, *(const u32x4*)&Alo[e0]);
            bf16x8 al1 = __builtin_bit_cast(bf16x8, *(const u32x4*)&Alo[e1]);
            bf16x8 al2 = __builtin_bit_cast(bf16x8, *(const u32x4*)&Alo[e2]);
            bf16x8 al3 = __builtin_bit_cast(bf16x8, *(const u32x4*)&Alo[e3]);
            bf16x8 bh  = __builtin_bit_cast(bf16x8, rbh);
            bf16x8 bl  = __builtin_bit_cast(bf16x8, rbl);

            acc0 = mfma16(ah0, bh, acc0);
            acc1 = mfma16(ah1, bh, acc1);
            acc2 = mfma16(ah2, bh, acc2);
            acc3 = mfma16(ah3, bh, acc3);
            acc0 = mfma16(al0, bh, acc0);
            acc1 = mfma16(al1, bh, acc1);
            acc2 = mfma16(al2, bh, acc2);
            acc3 = mfma16(al3, bh, acc3);
            acc0 = mfma16(ah0, bl, acc0);
            acc1 = mfma16(ah1, bl, acc1);
            acc2 = mfma16(ah2, bl, acc2);
            acc3 = mfma16(ah3, bl, acc3);
        }

        __syncthreads();

        const float bL = args.bias[L][n];

        if (L < 7) {
            #pragma unroll
            for (int j = 0; j < 4; ++j) {
                float d[13];
                #pragma unroll
                for (int c = 0; c < 13; ++c)
                    d[c] = (j == 0) ? acc0[c] : (j == 1) ? acc1[c] : (j == 2) ? acc2[c] : acc3[c];
                d[0] += bL;
                tanh_jet(d);
                store_jet(d, j);
            }
            __syncthreads();
        } else {
            const float wp = args.W8[n], wq = args.W8[128 + n];
            #pragma unroll
            for (int j = 0; j < 4; ++j) {
                float d[13];
                #pragma unroll
                for (int c = 0; c < 13; ++c)
                    d[c] = (j == 0) ? acc0[c] : (j == 1) ? acc1[c] : (j == 2) ? acc2[c] : acc3[c];
                d[0] += bL;
                tanh_jet(d);
                float rp[16];
                #pragma unroll
                for (int c = 0; c < 13; ++c) rp[c] = wp * d[c];
                rp[13] = wq * d[0]; rp[14] = wq * d[1]; rp[15] = wq * d[2];
                #pragma unroll
                for (int v = 0; v < 16; ++v) {
                    float s = rp[v];
                    s += __shfl_xor(s, 16); s += __shfl_xor(s, 8);
                    s += __shfl_xor(s, 4);  s += __shfl_xor(s, 2);
                    s += __shfl_xor(s, 1);
                    rp[v] = s;
                }
                if (ln31 == 0) {
                    #pragma unroll
                    for (int v = 0; v < 16; ++v) Part[wid][kh][j][v] = rp[v];
                }
            }
        }
    }

    __syncthreads();

    if (tid < 8) {
        const int p = tid, khp = p >> 2, jp = p & 3;
        float s[16];
        #pragma unroll
        for (int v = 0; v < 16; ++v)
            s[v] = Part[0][khp][jp][v] + Part[1][khp][jp][v]
                 + Part[2][khp][jp][v] + Part[3][khp][jp][v];

        float l1 = args.l1[0], l2 = args.l2[0];
        float u    = s[2];
        float v    = -s[1];
        float pv   = s[13] + args.b8[1];
        float u_t  = s[8];
        float v_t  = -s[7];
        float u_x  = s[5];
        float u_y  = s[6];
        float v_x  = -s[4];
        float v_y  = -s[5];
        float u_xx = s[10];
        float u_yy = s[12];
        float v_xx = -s[9];
        float v_yy = -s[11];
        float p_x = s[14], p_y = s[15];
        float f_u = u_t + l1 * (u * u_x + v * u_y) + p_x - l2 * (u_xx + u_yy);
        float f_v = v_t + l1 * (u * v_x + v * v_y) + p_y - l2 * (v_xx + v_yy);
        const int pt = pbase + p;
        float* out = args.out;
        out[0 * NPTS + pt] = u;
        out[1 * NPTS + pt] = v;
        out[2 * NPTS + pt] = pv;
        out[3 * NPTS + pt] = f_u;
        out[4 * NPTS + pt] = f_v;
    }
}

extern "C" void kernel_launch(void* const* d_in, const int* in_sizes, int n_in,
                              void* d_out, int out_size, void* d_ws, size_t ws_size,
                              hipStream_t stream) {
    PrepArgs pa;
    for (int i = 0; i < 7; ++i) pa.W[i] = (const float*)d_in[2 * (i + 1)];
    pa.dst = (u32x4*)d_ws;   // 448 KB
    pack_w_kernel<<<56, 256, 0, stream>>>(pa);

    Args a;
    a.W0 = (const float*)d_in[0];
    a.b0 = (const float*)d_in[1];
    a.bias[0] = nullptr;
    for (int L = 1; L <= 7; ++L) a.bias[L] = (const float*)d_in[2 * L + 1];
    a.W8 = (const float*)d_in[16];
    a.b8 = (const float*)d_in[17];
    a.xs = (const float*)d_in[18];
    a.ys = (const float*)d_in[19];
    a.ts = (const float*)d_in[20];
    a.l1 = (const float*)d_in[21];
    a.l2 = (const float*)d_in[22];
    a.wpk = (const u32x4*)d_ws;
    a.out = (float*)d_out;

    pinn_red16_kernel<<<NPTS / 16, 256, 0, stream>>>(a);  // runs iff lambda == 0
    pinn_mfma6_kernel<<<NPTS / 8, 256, 0, stream>>>(a);   // runs iff lambda != 0
}